// Round 9
// baseline (189.812 us; speedup 1.0000x reference)
//
#include <hip/hip_runtime.h>
#include <hip/hip_bf16.h>

typedef __bf16 bf16x8 __attribute__((ext_vector_type(8)));
typedef __bf16 bf16x4 __attribute__((ext_vector_type(4)));
typedef float f32x4 __attribute__((ext_vector_type(4)));

#define B_ 2
#define S_ 2048
#define D_ 1024
#define H_ 16
#define HD_ 64
#define NT_ (S_ / 64)   // 32 k-tiles total
#define NSPLIT 2
#define KT_PER (NT_ / NSPLIT)   // 16 tiles per split

__device__ inline void load_lds16(const __bf16* g, __bf16* l) {
  __builtin_amdgcn_global_load_lds(
      (const __attribute__((address_space(1))) void*)g,
      (__attribute__((address_space(3))) void*)l, 16, 0, 0);
}

// ---------------------------------------------------------------------------
// prep: z<3  -> transpose+convert W_z (fp32 [k][n]) to bf16 WT[z][n][k]
//       z==3 -> convert X fp32 -> bf16 (same layout)
// ---------------------------------------------------------------------------
__global__ __launch_bounds__(256) void prep(
    const float* __restrict__ X,
    const float* __restrict__ Wq, const float* __restrict__ Wk,
    const float* __restrict__ Wv,
    __bf16* __restrict__ Xb, __bf16* __restrict__ WT)
{
  const int z = blockIdx.z, t = threadIdx.x;
  if (z == 3) {
    size_t base = ((size_t)(blockIdx.y * 16 + blockIdx.x)) * 16384 + t * 4;
#pragma unroll
    for (int i = 0; i < 16; ++i) {
      size_t idx = base + (size_t)i * 1024;
      f32x4 v = *(const f32x4*)(X + idx);
      __bf16 o[4];
#pragma unroll
      for (int j = 0; j < 4; ++j) o[j] = (__bf16)v[j];
      *(ulong1*)(Xb + idx) = *(ulong1*)o;
    }
    return;
  }
  const float* W = (z == 0) ? Wq : (z == 1) ? Wk : Wv;
  __bf16* WTz = WT + (size_t)z * D_ * D_;
  const int k0 = blockIdx.y * 64, n0 = blockIdx.x * 64;

  __shared__ __bf16 T[64 * 72];
  {
    int kl = t >> 2, cg = (t & 3) * 16;
    const float* wp = W + (size_t)(k0 + kl) * D_ + n0 + cg;
    bf16x8 a, b;
#pragma unroll
    for (int j = 0; j < 4; ++j) { a[j] = (__bf16)wp[j];     a[4 + j] = (__bf16)wp[4 + j]; }
#pragma unroll
    for (int j = 0; j < 4; ++j) { b[j] = (__bf16)wp[8 + j]; b[4 + j] = (__bf16)wp[12 + j]; }
    *(bf16x8*)(T + kl * 72 + cg) = a;
    *(bf16x8*)(T + kl * 72 + cg + 8) = b;
  }
  __syncthreads();
  {
    int nl = t >> 2, kc = (t & 3) * 16;
    bf16x8 a, b;
#pragma unroll
    for (int j = 0; j < 8; ++j) a[j] = T[(kc + j) * 72 + nl];
#pragma unroll
    for (int j = 0; j < 8; ++j) b[j] = T[(kc + 8 + j) * 72 + nl];
    __bf16* op = WTz + (size_t)(n0 + nl) * D_ + k0 + kc;
    *(bf16x8*)(op) = a;
    *(bf16x8*)(op + 8) = b;
  }
}

// ---------------------------------------------------------------------------
// QKV projection (m97 structure + XOR-swizzled LDS, unchanged from R8)
// ---------------------------------------------------------------------------
__global__ __launch_bounds__(256) void qkv_gemm(
    const __bf16* __restrict__ Xb, const __bf16* __restrict__ WT,
    const float* __restrict__ bq, const float* __restrict__ bk,
    const float* __restrict__ bv,
    __bf16* __restrict__ Qw, __bf16* __restrict__ Kw, __bf16* __restrict__ VTw)
{
  const int z = blockIdx.z;
  const __bf16* Wz = WT + (size_t)z * D_ * D_;
  const float* bias = (z == 0) ? bq : (z == 1) ? bk : bv;
  __bf16* outp = (z == 0) ? Qw : (z == 1) ? Kw : VTw;
  const float mult = (z == 0) ? 0.125f * 1.44269504088896f : 1.0f;

  const int tid  = threadIdx.x;
  const int wave = tid >> 6, lane = tid & 63, ln = lane & 15, quad = lane >> 4;
  const int m0 = blockIdx.y * 128, n0 = blockIdx.x * 128;
  const int wm = (wave & 1) * 64, wn = (wave >> 1) * 64;

  __shared__ __bf16 Als[128 * 32];
  __shared__ __bf16 Bls[128 * 32];

  f32x4 acc[4][4] = {};

  for (int k0 = 0; k0 < D_; k0 += 32) {
    __syncthreads();
#pragma unroll
    for (int i = 0; i < 2; ++i) {
      int cb = wave * 128 + i * 64;
      int chunk = cb + lane;
      int row = chunk >> 2, c = chunk & 3;
      int gc = c ^ (row & 3);
      load_lds16(Xb + (size_t)(m0 + row) * D_ + k0 + gc * 8, Als + cb * 8);
      load_lds16(Wz + (size_t)(n0 + row) * D_ + k0 + gc * 8, Bls + cb * 8);
    }
    __syncthreads();

    bf16x8 af[4], bfr[4];
    const int dsw = (quad ^ (ln & 3)) * 8;
#pragma unroll
    for (int mt = 0; mt < 4; ++mt)
      af[mt] = *(const bf16x8*)(Als + (wm + mt * 16 + ln) * 32 + dsw);
#pragma unroll
    for (int nt = 0; nt < 4; ++nt)
      bfr[nt] = *(const bf16x8*)(Bls + (wn + nt * 16 + ln) * 32 + dsw);
#pragma unroll
    for (int mt = 0; mt < 4; ++mt)
#pragma unroll
      for (int nt = 0; nt < 4; ++nt)
        acc[mt][nt] = __builtin_amdgcn_mfma_f32_16x16x32_bf16(af[mt], bfr[nt], acc[mt][nt], 0, 0, 0);
  }

#pragma unroll
  for (int nt = 0; nt < 4; ++nt) {
    int n_g = n0 + wn + nt * 16 + ln;
    float bv_ = bias[n_g];
#pragma unroll
    for (int mt = 0; mt < 4; ++mt) {
      if (z < 2) {
#pragma unroll
        for (int r = 0; r < 4; ++r) {
          int m_g = m0 + wm + mt * 16 + quad * 4 + r;
          outp[(size_t)m_g * D_ + n_g] = (__bf16)((acc[mt][nt][r] + bv_) * mult);
        }
      } else {
        int m_g0 = m0 + wm + mt * 16 + quad * 4;
        bf16x4 v4;
#pragma unroll
        for (int r = 0; r < 4; ++r) v4[r] = (__bf16)(acc[mt][nt][r] + bv_);
        *(bf16x4*)(outp + (size_t)(m_g0 >> 11) * D_ * S_ + (size_t)n_g * S_ + (m_g0 & (S_ - 1))) = v4;
      }
    }
  }
}

// ---------------------------------------------------------------------------
// Flash attention v5: split-K 2-way -> grid 1024 WGs (4/CU resident).
// Single-buffer K/V LDS (34KB -> 4 WG/CU) + register prefetch one full
// compute-phase ahead. XOR-swizzled LDS; ones-rows PV row sums; unnormalized
// exp2 softmax. Splits combine by fp32 atomicAdd into O and L (linear).
// ---------------------------------------------------------------------------
__global__ __launch_bounds__(256) void attn(
    const __bf16* __restrict__ Q, const __bf16* __restrict__ K,
    const __bf16* __restrict__ VT, float* __restrict__ O,
    float* __restrict__ L)
{
  const int tid  = threadIdx.x;
  const int wave = tid >> 6, lane = tid & 63, ln = lane & 15, quad = lane >> 4;

  const int f = blockIdx.x;
  const int xcd = f & 7, g = f >> 3;
  const int bh = ((g & 3) << 3) | xcd;   // 4 bh-groups per XCD (2MB K/V in L2)
  const int rest = g >> 2;               // 0..31
  const int qt = rest & 15;              // q tile (128 rows)
  const int sk = rest >> 4;              // key split 0..1
  const int b = bh >> 4, h = bh & 15;
  const int q0 = qt * 128 + wave * 32;
  const int kt0 = sk * KT_PER, kt1 = kt0 + KT_PER;

  // Q B-frags (regs whole kernel)
  const __bf16* Qbase = Q + (size_t)(b * S_ + q0) * D_ + h * HD_;
  bf16x8 qb[2][2];
#pragma unroll
  for (int nt = 0; nt < 2; ++nt)
#pragma unroll
    for (int ks = 0; ks < 2; ++ks)
      qb[nt][ks] = *(const bf16x8*)(Qbase + (size_t)(nt * 16 + ln) * D_ + ks * 32 + quad * 8);

  const __bf16* Kh = K + (size_t)b * S_ * D_ + h * HD_;        // [key][d]
  const __bf16* Vh = VT + (size_t)(b * D_ + h * HD_) * S_;     // [d][s]

  __shared__ __bf16 Kls[64 * 64];      // [key][d], swizzled chunks (8KB)
  __shared__ __bf16 Vls[80 * 64];      // [d][key] + ones rows 64..79 (10KB)
  __shared__ __bf16 Pls[4][32 * 64];   // per-wave P[q][key] (16KB)
  __bf16* Pw = Pls[wave];

  // ones rows (written once; staging never touches rows 64..79)
  if (tid < 128) {
    bf16x8 ones;
#pragma unroll
    for (int j = 0; j < 8; ++j) ones[j] = (__bf16)1.0f;
    int rr = tid >> 3, cc = tid & 7;
    *(bf16x8*)(&Vls[(64 + rr) * 64 + cc * 8]) = ones;
  }

  f32x4 acc[2][5] = {};                // [q-mt][d-tile 0..3, 4 = row-sum]
  const int swl = ln & 7;

  // prefetch first tile into regs
  bf16x8 kreg[2], vreg[2];
#pragma unroll
  for (int i = 0; i < 2; ++i) {
    int chunk = i * 256 + tid, row = chunk >> 3, cc = chunk & 7;
    kreg[i] = *(const bf16x8*)(Kh + (size_t)(kt0 * 64 + row) * D_ + cc * 8);
    vreg[i] = *(const bf16x8*)(Vh + (size_t)row * S_ + kt0 * 64 + cc * 8);
  }

  for (int kt = kt0; kt < kt1; ++kt) {
    __syncthreads();   // prior compute's LDS reads complete
#pragma unroll
    for (int i = 0; i < 2; ++i) {
      int chunk = i * 256 + tid, row = chunk >> 3, cc = chunk & 7;
      int sw = (cc ^ (row & 7)) * 8;
      *(bf16x8*)(Kls + row * 64 + sw) = kreg[i];
      *(bf16x8*)(Vls + row * 64 + sw) = vreg[i];
    }
    if (kt + 1 < kt1) {
#pragma unroll
      for (int i = 0; i < 2; ++i) {
        int chunk = i * 256 + tid, row = chunk >> 3, cc = chunk & 7;
        kreg[i] = *(const bf16x8*)(Kh + (size_t)((kt + 1) * 64 + row) * D_ + cc * 8);
        vreg[i] = *(const bf16x8*)(Vh + (size_t)row * S_ + (kt + 1) * 64 + cc * 8);
      }
    }
    __syncthreads();   // staging visible

    // S^T = K * Q^T  (C: row=key(quad*4+r), col=q(ln))
    f32x4 st[4][2] = {};
#pragma unroll
    for (int mt = 0; mt < 4; ++mt) {
#pragma unroll
      for (int ks = 0; ks < 2; ++ks) {
        bf16x8 ka = *(const bf16x8*)(Kls + (mt * 16 + ln) * 64 + ((ks * 4 + quad) ^ swl) * 8);
#pragma unroll
        for (int nt = 0; nt < 2; ++nt)
          st[mt][nt] = __builtin_amdgcn_mfma_f32_16x16x32_bf16(ka, qb[nt][ks], st[mt][nt], 0, 0, 0);
      }
    }

    // exp2; pack 4 consecutive keys -> swizzled ds_write_b64 (A-layout)
#pragma unroll
    for (int mt = 0; mt < 4; ++mt)
#pragma unroll
      for (int nt = 0; nt < 2; ++nt) {
        bf16x4 pk;
#pragma unroll
        for (int r = 0; r < 4; ++r)
          pk[r] = (__bf16)__builtin_amdgcn_exp2f(st[mt][nt][r]);
        *(bf16x4*)(Pw + (nt * 16 + ln) * 64 + ((2 * mt + (quad >> 1)) ^ swl) * 8 + (quad & 1) * 4) = pk;
      }

    // O += P * V (+ ones n-tile -> row sums); same-wave P round-trip
#pragma unroll
    for (int ks = 0; ks < 2; ++ks) {
      bf16x8 pa[2];
#pragma unroll
      for (int mt = 0; mt < 2; ++mt)
        pa[mt] = *(const bf16x8*)(Pw + (mt * 16 + ln) * 64 + ((ks * 4 + quad) ^ swl) * 8);
#pragma unroll
      for (int dt = 0; dt < 5; ++dt) {
        int vrow = (dt < 4) ? dt * 16 + ln : 64 + ln;
        bf16x8 vb = *(const bf16x8*)(Vls + vrow * 64 + ((ks * 4 + quad) ^ swl) * 8);
#pragma unroll
        for (int mt = 0; mt < 2; ++mt)
          acc[mt][dt] = __builtin_amdgcn_mfma_f32_16x16x32_bf16(pa[mt], vb, acc[mt][dt], 0, 0, 0);
      }
    }
  }

  // combine across splits: atomic fp32 adds (linear accumulation)
  if (ln == 0) {
#pragma unroll
    for (int mt = 0; mt < 2; ++mt)
#pragma unroll
      for (int r = 0; r < 4; ++r)
        atomicAdd(&L[(size_t)bh * S_ + q0 + mt * 16 + quad * 4 + r], acc[mt][4][r]);
  }
#pragma unroll
  for (int mt = 0; mt < 2; ++mt)
#pragma unroll
    for (int r = 0; r < 4; ++r) {
      float* op = O + (size_t)(b * S_ + q0 + mt * 16 + quad * 4 + r) * D_ + h * HD_;
#pragma unroll
      for (int dt = 0; dt < 4; ++dt)
        atomicAdd(&op[dt * 16 + ln], acc[mt][dt][r]);
    }
}

// normalize: O[b][s][h*64+d] /= L[bh][s]
__global__ __launch_bounds__(256) void norm_kernel(float* __restrict__ O,
                                                   const float* __restrict__ L)
{
  int idx = (blockIdx.x * 256 + threadIdx.x) * 4;
  int col = idx & (D_ - 1);
  int h = col >> 6;
  int bs = idx >> 10;
  int b = bs >> 11, s = bs & (S_ - 1);
  float linv = 1.0f / L[(size_t)(b * H_ + h) * S_ + s];
  f32x4 v = *(const f32x4*)(O + idx);
  v *= linv;
  *(f32x4*)(O + idx) = v;
}

extern "C" void kernel_launch(void* const* d_in, const int* in_sizes, int n_in,
                              void* d_out, int out_size, void* d_ws, size_t ws_size,
                              hipStream_t stream) {
  const float* X  = (const float*)d_in[0];
  const float* Wq = (const float*)d_in[1];
  const float* bq = (const float*)d_in[2];
  const float* Wk = (const float*)d_in[3];
  const float* bk = (const float*)d_in[4];
  const float* Wv = (const float*)d_in[5];
  const float* bv = (const float*)d_in[6];

  __bf16* Qw  = (__bf16*)d_ws;                        // 8 MB
  __bf16* Kw  = Qw  + (size_t)B_ * S_ * D_;           // 8 MB
  __bf16* VTw = Kw  + (size_t)B_ * S_ * D_;           // 8 MB
  __bf16* Xb  = VTw + (size_t)B_ * S_ * D_;           // 8 MB
  __bf16* WT  = Xb  + (size_t)B_ * S_ * D_;           // 6 MB
  float*  Lb  = (float*)(WT + (size_t)3 * D_ * D_);   // 256 KB
  float* out = (float*)d_out;

  prep<<<dim3(16, 16, 4), 256, 0, stream>>>(X, Wq, Wk, Wv, Xb, WT);
  qkv_gemm<<<dim3(8, 32, 3), 256, 0, stream>>>(Xb, WT, bq, bk, bv, Qw, Kw, VTw);

  hipMemsetAsync(out, 0, (size_t)B_ * S_ * D_ * sizeof(float), stream);
  hipMemsetAsync(Lb, 0, (size_t)B_ * H_ * S_ * sizeof(float), stream);

  attn<<<1024, 256, 0, stream>>>(Qw, Kw, VTw, out, Lb);
  norm_kernel<<<(B_ * S_ * D_ / 4) / 256, 256, 0, stream>>>(out, Lb);
}